// Round 3
// baseline (491.663 us; speedup 1.0000x reference)
//
#include <hip/hip_runtime.h>
#include <math.h>

#define EMB 256
#define HEADS 8
#define HD 32
#define BATCH 2
#define SEQ 4096
#define QSCALE 0.25504672075827703f   // (1/sqrt(32)) * log2(e)  -- exp2-folded softmax scale

typedef __attribute__((ext_vector_type(8))) _Float16 f16x8;
typedef __attribute__((ext_vector_type(4))) _Float16 f16x4;
typedef __attribute__((ext_vector_type(2))) __fp16 fp16x2_native;
typedef __attribute__((ext_vector_type(4))) float f32x4;
typedef unsigned int uint_t;

__device__ __forceinline__ uint_t pk16(float a, float b) {
    union { fp16x2_native h; uint_t u; } cv;
    cv.h = __builtin_amdgcn_cvt_pkrtz(a, b);
    return cv.u;
}

#define MFMA16(A, B, C) __builtin_amdgcn_mfma_f32_16x16x32_f16(A, B, C, 0, 0, 0)

// ---------------------------------------------------------------------------
// Prep 1: query fp32 -> Xh/Xl fp16 hi/lo split.  [r=b*4096+s][256]
// ---------------------------------------------------------------------------
__global__ __launch_bounds__(256) void prep_x_kernel(
    const float* __restrict__ q, _Float16* __restrict__ Xh, _Float16* __restrict__ Xl)
{
    const int i = (blockIdx.x * 256 + threadIdx.x) * 8;
    float4 v0 = *(const float4*)(q + i);
    float4 v1 = *(const float4*)(q + i + 4);
    float xs[8] = {v0.x, v0.y, v0.z, v0.w, v1.x, v1.y, v1.z, v1.w};
    f16x8 hv, lv;
    #pragma unroll
    for (int j = 0; j < 8; j++) {
        _Float16 h = (_Float16)xs[j];
        hv[j] = h;
        lv[j] = (_Float16)(xs[j] - (float)h);
    }
    *(f16x8*)(Xh + i) = hv;
    *(f16x8*)(Xl + i) = lv;
}

// ---------------------------------------------------------------------------
// Prep 2: weights -> transposed fp16 hi/lo.
//   Wth/Wtl: [p][h][e=32][d=256], QSCALE folded into p==0 (Wq)
//   WoTh/WoTl: [o=256][he=256]
// ---------------------------------------------------------------------------
__global__ __launch_bounds__(256) void prep_w_kernel(
    const float* __restrict__ wq, const float* __restrict__ wk,
    const float* __restrict__ wv, const float* __restrict__ wo,
    _Float16* __restrict__ Wth, _Float16* __restrict__ Wtl,
    _Float16* __restrict__ WoTh, _Float16* __restrict__ WoTl)
{
    for (int t = blockIdx.x * 256 + threadIdx.x; t < 262144; t += 256 * 256) {
        if (t < 196608) {
            int d = t & 255, e = (t >> 8) & 31, ph = t >> 13;
            int p = ph >> 3, h = ph & 7;
            const float* w = (p == 0) ? wq : (p == 1 ? wk : wv);
            float val = w[h * 8192 + d * 32 + e] * ((p == 0) ? QSCALE : 1.0f);
            _Float16 hi = (_Float16)val;
            Wth[t] = hi;
            Wtl[t] = (_Float16)(val - (float)hi);
        } else {
            int t2 = t - 196608;
            int he = t2 & 255, o = t2 >> 8;
            float val = wo[(he >> 5) * 8192 + (he & 31) * 256 + o];
            _Float16 hi = (_Float16)val;
            WoTh[t2] = hi;
            WoTl[t2] = (_Float16)(val - (float)hi);
        }
    }
}

// ---------------------------------------------------------------------------
// Kernel 1: QKV projection as MFMA GEMM, no LDS staging of operands.
// grid (128, 24): x = 64-row tile (wave = 16 rows), y = p*8+h.
// D[s][e] = Xh*Wh + Xl*Wh + Xh*Wl   (fp32-grade via hi/lo split)
// Q/K: LDS-staged 64B-row writes.  V: direct VT[e][s] f16x4 writes.
// ---------------------------------------------------------------------------
__global__ __launch_bounds__(256) void qkv_gemm_kernel(
    const _Float16* __restrict__ Xh, const _Float16* __restrict__ Xl,
    const _Float16* __restrict__ Wth, const _Float16* __restrict__ Wtl,
    _Float16* __restrict__ Qf, _Float16* __restrict__ Kf, _Float16* __restrict__ VT)
{
    __shared__ _Float16 st[4][16][32];
    const int t = threadIdx.x, w = t >> 6, l = t & 63, lo4 = l & 15, g = l >> 4;
    const int tile = blockIdx.x, ph = blockIdx.y, p = ph >> 3, h = ph & 7;
    const int r0 = tile * 64 + w * 16;
    const int b = (tile * 64) >> 12;
    const int s_base = (tile * 64) & (SEQ - 1);
    const int hb = h * BATCH + b;

    f16x8 Ah[8], Al[8];
    const size_t xoff = (size_t)(r0 + lo4) * 256 + g * 8;
    #pragma unroll
    for (int kc = 0; kc < 8; kc++) {
        Ah[kc] = *(const f16x8*)(Xh + xoff + kc * 32);
        Al[kc] = *(const f16x8*)(Xl + xoff + kc * 32);
    }

    f32x4 D[2];
    #pragma unroll
    for (int ct = 0; ct < 2; ct++) {
        f32x4 acc = {0.f, 0.f, 0.f, 0.f};
        const size_t woff = (size_t)(ph * 32 + ct * 16 + lo4) * 256 + g * 8;
        #pragma unroll
        for (int kc = 0; kc < 8; kc++) {
            f16x8 Bh = *(const f16x8*)(Wth + woff + kc * 32);
            f16x8 Bl = *(const f16x8*)(Wtl + woff + kc * 32);
            acc = MFMA16(Ah[kc], Bh, acc);
            acc = MFMA16(Al[kc], Bh, acc);
            acc = MFMA16(Ah[kc], Bl, acc);
        }
        D[ct] = acc;
    }

    if (p < 2) {
        #pragma unroll
        for (int ct = 0; ct < 2; ct++)
            #pragma unroll
            for (int r = 0; r < 4; r++)
                st[w][g * 4 + r][ct * 16 + lo4] = (_Float16)D[ct][r];
        __syncthreads();
        _Float16* dst = (p == 0) ? Qf : Kf;
        const int rl = t >> 2, e8 = (t & 3) * 8;   // rl = 0..63 local row
        *(f16x8*)(dst + ((size_t)hb * SEQ + s_base + rl) * HD + e8) =
            *(f16x8*)&st[rl >> 4][rl & 15][e8];
    } else {
        #pragma unroll
        for (int ct = 0; ct < 2; ct++) {
            f16x4 v;
            #pragma unroll
            for (int r = 0; r < 4; r++) v[r] = (_Float16)D[ct][r];
            *(f16x4*)(VT + ((size_t)hb * HD + ct * 16 + lo4) * SEQ + s_base + w * 16 + g * 4) = v;
        }
    }
}

// ---------------------------------------------------------------------------
// Kernel 2: fused attention, two-pass no-max softmax (exp2-domain), fp16 MFMA.
// Round-10: round-0 compute structure (K=32 PV + shuffle network restored).
// ONE change: attn_out stores are LDS-STAGED per wave.  Each wave buffers a
// [32 q][64 k] fp32 chunk (stride 68 -> conflict-free b128 writes) and
// flushes it with 8 dwordx4 stores = 128B-contiguous-per-row bursts (256B
// per row per flush), replacing the 64B-granule 16KB-strided direct stores
// whose ~262k interleaved streams held HBM write efficiency at ~43%.
// Hred is overlaid on the same per-wave LDS region (Pst dead by then).
// ---------------------------------------------------------------------------
__global__ __launch_bounds__(256) void attn_kernel(
    const _Float16* __restrict__ Qf, const _Float16* __restrict__ Kf,
    const _Float16* __restrict__ VT,
    float* __restrict__ attn_out,     // [hb][q][k]
    _Float16* __restrict__ heads)     // [hb][q][e] fp16
{
    __shared__ float lred[4][2][16];
    __shared__ __align__(16) char smem_raw[4][8704];   // per-wave: Pst[32][68] f32, later Hred[32][33] f32

    const int tid = threadIdx.x;
    const int w = tid >> 6;
    const int l = tid & 63;
    const int lo4 = l & 15;
    const int g = l >> 4;
    // XCD swizzle: 2048 blocks = 16 hb x 128 qtiles; hb%8 == bid%8 == XCD
    const int bid = blockIdx.x;
    const int xcd = bid & 7;
    const int j = bid >> 3;
    const int hb = xcd + 8 * (j >> 7);
    const int q0 = (j & 127) * 32;

    float (*Pst)[68] = reinterpret_cast<float(*)[68]>(smem_raw[w]);

    const _Float16* Qb = Qf + (size_t)hb * SEQ * HD;
    const _Float16* Kb = Kf + (size_t)hb * SEQ * HD;
    const _Float16* Vb = VT + (size_t)hb * HD * SEQ;

    const f16x8 Bq0 = *(const f16x8*)(Qb + (size_t)(q0 + lo4) * HD + g * 8);
    const f16x8 Bq1 = *(const f16x8*)(Qb + (size_t)(q0 + 16 + lo4) * HD + g * 8);

    const int c_lo = w * 32;   // contiguous per-wave k-range: c in [c_lo, c_lo+32)

    // ---------- pass A: row sums of exp2(s) ----------
    float ls0 = 0.f, ls1 = 0.f;
    for (int c = c_lo; c < c_lo + 32; c++) {
        const int k0 = c * 32;
        #pragma unroll
        for (int s = 0; s < 2; s++) {
            f16x8 Ak = *(const f16x8*)(Kb + (size_t)(k0 + s * 16 + lo4) * HD + g * 8);
            f32x4 D0 = {0.f, 0.f, 0.f, 0.f}, D1 = {0.f, 0.f, 0.f, 0.f};
            D0 = MFMA16(Ak, Bq0, D0);
            D1 = MFMA16(Ak, Bq1, D1);
            ls0 += exp2f(D0[0]) + exp2f(D0[1]) + exp2f(D0[2]) + exp2f(D0[3]);
            ls1 += exp2f(D1[0]) + exp2f(D1[1]) + exp2f(D1[2]) + exp2f(D1[3]);
        }
    }
    ls0 += __shfl_xor(ls0, 16, 64); ls0 += __shfl_xor(ls0, 32, 64);
    ls1 += __shfl_xor(ls1, 16, 64); ls1 += __shfl_xor(ls1, 32, 64);
    if (l < 16) { lred[w][0][lo4] = ls0; lred[w][1][lo4] = ls1; }
    __syncthreads();
    const float inv0 = 1.0f / (lred[0][0][lo4] + lred[1][0][lo4] + lred[2][0][lo4] + lred[3][0][lo4]);
    const float inv1 = 1.0f / (lred[0][1][lo4] + lred[1][1][lo4] + lred[2][1][lo4] + lred[3][1][lo4]);

    // ---------- pass B: recompute, stage probs in LDS, burst-flush, PV ----------
    f32x4 H00 = {0.f,0.f,0.f,0.f}, H01 = {0.f,0.f,0.f,0.f};
    f32x4 H10 = {0.f,0.f,0.f,0.f}, H11 = {0.f,0.f,0.f,0.f};
    const int src0 = lo4 + ((g & 1) * 2) * 16;
    const int src1 = src0 + 16;
    float* arow = attn_out + ((size_t)hb * SEQ + q0) * SEQ;

    for (int cp = 0; cp < 16; cp++) {
        #pragma unroll
        for (int ci = 0; ci < 2; ci++) {
            const int c = c_lo + cp * 2 + ci;
            const int k0 = c * 32;
            uint_t w00[2], w01[2], w10[2], w11[2];
            #pragma unroll
            for (int s = 0; s < 2; s++) {
                f16x8 Ak = *(const f16x8*)(Kb + (size_t)(k0 + s * 16 + lo4) * HD + g * 8);
                f32x4 D0 = {0.f, 0.f, 0.f, 0.f}, D1 = {0.f, 0.f, 0.f, 0.f};
                D0 = MFMA16(Ak, Bq0, D0);
                D1 = MFMA16(Ak, Bq1, D1);
                float p00 = exp2f(D0[0]) * inv0, p01 = exp2f(D0[1]) * inv0;
                float p02 = exp2f(D0[2]) * inv0, p03 = exp2f(D0[3]) * inv0;
                float p10 = exp2f(D1[0]) * inv1, p11 = exp2f(D1[1]) * inv1;
                float p12 = exp2f(D1[2]) * inv1, p13 = exp2f(D1[3]) * inv1;
                const int col = ci * 32 + s * 16 + g * 4;
                *(f32x4*)&Pst[lo4][col]      = (f32x4){p00, p01, p02, p03};
                *(f32x4*)&Pst[16 + lo4][col] = (f32x4){p10, p11, p12, p13};
                w00[s] = pk16(p00, p01); w01[s] = pk16(p02, p03);
                w10[s] = pk16(p10, p11); w11[s] = pk16(p12, p13);
            }
            union { f16x8 v; uint_t u[4]; } P0, P1;
            {
                uint_t a, b2;
                a = __shfl(w00[0], src0, 64); b2 = __shfl(w00[1], src0, 64); P0.u[0] = (g >= 2) ? b2 : a;
                a = __shfl(w01[0], src0, 64); b2 = __shfl(w01[1], src0, 64); P0.u[1] = (g >= 2) ? b2 : a;
                a = __shfl(w00[0], src1, 64); b2 = __shfl(w00[1], src1, 64); P0.u[2] = (g >= 2) ? b2 : a;
                a = __shfl(w01[0], src1, 64); b2 = __shfl(w01[1], src1, 64); P0.u[3] = (g >= 2) ? b2 : a;
                a = __shfl(w10[0], src0, 64); b2 = __shfl(w10[1], src0, 64); P1.u[0] = (g >= 2) ? b2 : a;
                a = __shfl(w11[0], src0, 64); b2 = __shfl(w11[1], src0, 64); P1.u[1] = (g >= 2) ? b2 : a;
                a = __shfl(w10[0], src1, 64); b2 = __shfl(w10[1], src1, 64); P1.u[2] = (g >= 2) ? b2 : a;
                a = __shfl(w11[0], src1, 64); b2 = __shfl(w11[1], src1, 64); P1.u[3] = (g >= 2) ? b2 : a;
            }
            f16x8 Av0 = *(const f16x8*)(Vb + (size_t)lo4 * SEQ + k0 + g * 8);
            f16x8 Av1 = *(const f16x8*)(Vb + (size_t)(16 + lo4) * SEQ + k0 + g * 8);
            H00 = MFMA16(Av0, P0.v, H00);
            H01 = MFMA16(Av1, P0.v, H01);
            H10 = MFMA16(Av0, P1.v, H10);
            H11 = MFMA16(Av1, P1.v, H11);
        }
        // ---- flush 64-k chunk: 128B-contiguous-per-row bursts ----
        {
            const int kb = (c_lo + cp * 2) * 32;
            const int row = (l >> 3);
            const int colb = (l & 7) * 4;
            #pragma unroll
            for (int rb = 0; rb < 4; rb++) {
                const int rr = rb * 8 + row;
                float* dst = arow + (size_t)rr * SEQ + kb + colb;
                *(f32x4*)(dst)      = *(f32x4*)&Pst[rr][colb];
                *(f32x4*)(dst + 32) = *(f32x4*)&Pst[rr][colb + 32];
            }
        }
    }

    // ---- Hred overlaid on Pst region (same wave: LDS in-order; then barrier) ----
    float (*HredW)[33] = reinterpret_cast<float(*)[33]>(smem_raw[w]);
    #pragma unroll
    for (int r = 0; r < 4; r++) {
        HredW[lo4][g * 4 + r]            = H00[r];
        HredW[lo4][16 + g * 4 + r]       = H01[r];
        HredW[16 + lo4][g * 4 + r]       = H10[r];
        HredW[16 + lo4][16 + g * 4 + r]  = H11[r];
    }
    __syncthreads();
    for (int i = tid; i < 32 * 32; i += 256) {
        int qq = i >> 5, e = i & 31;
        float sum = 0.f;
        #pragma unroll
        for (int wv = 0; wv < 4; wv++)
            sum += reinterpret_cast<float(*)[33]>(smem_raw[wv])[qq][e];
        heads[((size_t)hb * SEQ + q0 + qq) * HD + e] = (_Float16)sum;
    }
}

// ---------------------------------------------------------------------------
// Kernel 3: output projection as MFMA GEMM.
// grid 128 x 256 thr: wave = 16 rows, all 256 out cols (16 col-tiles).
// out[r][o] = sum_he H[r][he] * (WoTh + WoTl)[o][he]
// ---------------------------------------------------------------------------
__global__ __launch_bounds__(256) void out_gemm_kernel(
    const _Float16* __restrict__ Hf,
    const _Float16* __restrict__ WoTh, const _Float16* __restrict__ WoTl,
    float* __restrict__ out)
{
    const int t = threadIdx.x, w = t >> 6, l = t & 63, lo4 = l & 15, g = l >> 4;
    const int r0 = blockIdx.x * 64 + w * 16;
    const int b = r0 >> 12;
    const int sb = r0 & (SEQ - 1);

    f16x8 A[8];
    #pragma unroll
    for (int kc = 0; kc < 8; kc++)
        A[kc] = *(const f16x8*)(Hf + (((size_t)(kc * BATCH + b)) * SEQ + sb + lo4) * HD + g * 8);

    for (int ct = 0; ct < 16; ct++) {
        f32x4 acc = {0.f, 0.f, 0.f, 0.f};
        const size_t woff = (size_t)(ct * 16 + lo4) * 256 + g * 8;
        #pragma unroll
        for (int kc = 0; kc < 8; kc++) {
            acc = MFMA16(A[kc], *(const f16x8*)(WoTh + woff + kc * 32), acc);
            acc = MFMA16(A[kc], *(const f16x8*)(WoTl + woff + kc * 32), acc);
        }
        #pragma unroll
        for (int r = 0; r < 4; r++)
            out[(size_t)(r0 + g * 4 + r) * 256 + ct * 16 + lo4] = acc[r];
    }
}

extern "C" void kernel_launch(void* const* d_in, const int* in_sizes, int n_in,
                              void* d_out, int out_size, void* d_ws, size_t ws_size,
                              hipStream_t stream) {
    const float* query = (const float*)d_in[0];
    const float* wq = (const float*)d_in[1];
    const float* wk = (const float*)d_in[2];
    const float* wv = (const float*)d_in[3];
    const float* wo = (const float*)d_in[4];
    float* out = (float*)d_out;
    float* attn_out = out + (size_t)BATCH * SEQ * EMB;

    _Float16* ws = (_Float16*)d_ws;
    const size_t nx  = (size_t)BATCH * SEQ * EMB;          // 2,097,152
    const size_t per = (size_t)HEADS * BATCH * SEQ * HD;   // 2,097,152
    _Float16* Xh   = ws;
    _Float16* Xl   = Xh + nx;
    _Float16* Wth  = Xl + nx;          // 196,608
    _Float16* Wtl  = Wth + 196608;
    _Float16* WoTh = Wtl + 196608;     // 65,536
    _Float16* WoTl = WoTh + 65536;
    _Float16* Qf   = WoTl + 65536;
    _Float16* Kf   = Qf + per;
    _Float16* VT   = Kf + per;
    _Float16* Hf   = VT + per;

    prep_x_kernel<<<(int)(nx / (256 * 8)), 256, 0, stream>>>(query, Xh, Xl);
    prep_w_kernel<<<256, 256, 0, stream>>>(wq, wk, wv, wo, Wth, Wtl, WoTh, WoTl);
    qkv_gemm_kernel<<<dim3((BATCH * SEQ) / 64, 3 * HEADS), 256, 0, stream>>>(
        Xh, Xl, Wth, Wtl, Qf, Kf, VT);
    attn_kernel<<<HEADS * BATCH * (SEQ / 32), 256, 0, stream>>>(
        Qf, Kf, VT, attn_out, Hf);
    out_gemm_kernel<<<(BATCH * SEQ) / 64, 256, 0, stream>>>(Hf, WoTh, WoTl, out);
}

// Round 4
// 438.845 us; speedup vs baseline: 1.1204x; 1.1204x over previous
//
#include <hip/hip_runtime.h>
#include <math.h>

#define EMB 256
#define HEADS 8
#define HD 32
#define BATCH 2
#define SEQ 4096
#define QSCALE 0.25504672075827703f   // (1/sqrt(32)) * log2(e)  -- exp2-folded softmax scale

typedef __attribute__((ext_vector_type(8))) _Float16 f16x8;
typedef __attribute__((ext_vector_type(4))) _Float16 f16x4;
typedef __attribute__((ext_vector_type(2))) __fp16 fp16x2_native;
typedef __attribute__((ext_vector_type(4))) float f32x4;
typedef unsigned int uint_t;

__device__ __forceinline__ uint_t pk16(float a, float b) {
    union { fp16x2_native h; uint_t u; } cv;
    cv.h = __builtin_amdgcn_cvt_pkrtz(a, b);
    return cv.u;
}

// Raw v_exp_f32 (2^x).  libm exp2f routes through OCML's denormal-guarded
// path (~5 extra VALU ops/call); our exponents are bounded so the bare
// instruction is exact enough.  Non-volatile asm -> scheduler can reorder.
__device__ __forceinline__ float fast_exp2(float x) {
    float r;
    asm("v_exp_f32 %0, %1" : "=v"(r) : "v"(x));
    return r;
}
__device__ __forceinline__ float fast_log2(float x) {
    float r;
    asm("v_log_f32 %0, %1" : "=v"(r) : "v"(x));
    return r;
}

#define MFMA16(A, B, C) __builtin_amdgcn_mfma_f32_16x16x32_f16(A, B, C, 0, 0, 0)

// ---------------------------------------------------------------------------
// Prep 1: query fp32 -> Xh/Xl fp16 hi/lo split.  [r=b*4096+s][256]
// ---------------------------------------------------------------------------
__global__ __launch_bounds__(256) void prep_x_kernel(
    const float* __restrict__ q, _Float16* __restrict__ Xh, _Float16* __restrict__ Xl)
{
    const int i = (blockIdx.x * 256 + threadIdx.x) * 8;
    float4 v0 = *(const float4*)(q + i);
    float4 v1 = *(const float4*)(q + i + 4);
    float xs[8] = {v0.x, v0.y, v0.z, v0.w, v1.x, v1.y, v1.z, v1.w};
    f16x8 hv, lv;
    #pragma unroll
    for (int j = 0; j < 8; j++) {
        _Float16 h = (_Float16)xs[j];
        hv[j] = h;
        lv[j] = (_Float16)(xs[j] - (float)h);
    }
    *(f16x8*)(Xh + i) = hv;
    *(f16x8*)(Xl + i) = lv;
}

// ---------------------------------------------------------------------------
// Prep 2: weights -> transposed fp16 hi/lo.
//   Wth/Wtl: [p][h][e=32][d=256], QSCALE folded into p==0 (Wq)
//   WoTh/WoTl: [o=256][he=256]
// ---------------------------------------------------------------------------
__global__ __launch_bounds__(256) void prep_w_kernel(
    const float* __restrict__ wq, const float* __restrict__ wk,
    const float* __restrict__ wv, const float* __restrict__ wo,
    _Float16* __restrict__ Wth, _Float16* __restrict__ Wtl,
    _Float16* __restrict__ WoTh, _Float16* __restrict__ WoTl)
{
    for (int t = blockIdx.x * 256 + threadIdx.x; t < 262144; t += 256 * 256) {
        if (t < 196608) {
            int d = t & 255, e = (t >> 8) & 31, ph = t >> 13;
            int p = ph >> 3, h = ph & 7;
            const float* w = (p == 0) ? wq : (p == 1 ? wk : wv);
            float val = w[h * 8192 + d * 32 + e] * ((p == 0) ? QSCALE : 1.0f);
            _Float16 hi = (_Float16)val;
            Wth[t] = hi;
            Wtl[t] = (_Float16)(val - (float)hi);
        } else {
            int t2 = t - 196608;
            int he = t2 & 255, o = t2 >> 8;
            float val = wo[(he >> 5) * 8192 + (he & 31) * 256 + o];
            _Float16 hi = (_Float16)val;
            WoTh[t2] = hi;
            WoTl[t2] = (_Float16)(val - (float)hi);
        }
    }
}

// ---------------------------------------------------------------------------
// Kernel 1: QKV projection as MFMA GEMM, no LDS staging of operands.
// grid (128, 24): x = 64-row tile (wave = 16 rows), y = p*8+h.
// D[s][e] = Xh*Wh + Xl*Wh + Xh*Wl   (fp32-grade via hi/lo split)
// Q/K: LDS-staged 64B-row writes.  V: direct VT[e][s] f16x4 writes.
// ---------------------------------------------------------------------------
__global__ __launch_bounds__(256) void qkv_gemm_kernel(
    const _Float16* __restrict__ Xh, const _Float16* __restrict__ Xl,
    const _Float16* __restrict__ Wth, const _Float16* __restrict__ Wtl,
    _Float16* __restrict__ Qf, _Float16* __restrict__ Kf, _Float16* __restrict__ VT)
{
    __shared__ _Float16 st[4][16][32];
    const int t = threadIdx.x, w = t >> 6, l = t & 63, lo4 = l & 15, g = l >> 4;
    const int tile = blockIdx.x, ph = blockIdx.y, p = ph >> 3, h = ph & 7;
    const int r0 = tile * 64 + w * 16;
    const int b = (tile * 64) >> 12;
    const int s_base = (tile * 64) & (SEQ - 1);
    const int hb = h * BATCH + b;

    f16x8 Ah[8], Al[8];
    const size_t xoff = (size_t)(r0 + lo4) * 256 + g * 8;
    #pragma unroll
    for (int kc = 0; kc < 8; kc++) {
        Ah[kc] = *(const f16x8*)(Xh + xoff + kc * 32);
        Al[kc] = *(const f16x8*)(Xl + xoff + kc * 32);
    }

    f32x4 D[2];
    #pragma unroll
    for (int ct = 0; ct < 2; ct++) {
        f32x4 acc = {0.f, 0.f, 0.f, 0.f};
        const size_t woff = (size_t)(ph * 32 + ct * 16 + lo4) * 256 + g * 8;
        #pragma unroll
        for (int kc = 0; kc < 8; kc++) {
            f16x8 Bh = *(const f16x8*)(Wth + woff + kc * 32);
            f16x8 Bl = *(const f16x8*)(Wtl + woff + kc * 32);
            acc = MFMA16(Ah[kc], Bh, acc);
            acc = MFMA16(Al[kc], Bh, acc);
            acc = MFMA16(Ah[kc], Bl, acc);
        }
        D[ct] = acc;
    }

    if (p < 2) {
        #pragma unroll
        for (int ct = 0; ct < 2; ct++)
            #pragma unroll
            for (int r = 0; r < 4; r++)
                st[w][g * 4 + r][ct * 16 + lo4] = (_Float16)D[ct][r];
        __syncthreads();
        _Float16* dst = (p == 0) ? Qf : Kf;
        const int rl = t >> 2, e8 = (t & 3) * 8;   // rl = 0..63 local row
        *(f16x8*)(dst + ((size_t)hb * SEQ + s_base + rl) * HD + e8) =
            *(f16x8*)&st[rl >> 4][rl & 15][e8];
    } else {
        #pragma unroll
        for (int ct = 0; ct < 2; ct++) {
            f16x4 v;
            #pragma unroll
            for (int r = 0; r < 4; r++) v[r] = (_Float16)D[ct][r];
            *(f16x4*)(VT + ((size_t)hb * HD + ct * 16 + lo4) * SEQ + s_base + w * 16 + g * 4) = v;
        }
    }
}

// ---------------------------------------------------------------------------
// Kernel 2: fused attention, two-pass no-max softmax (exp2-domain), fp16 MFMA.
// Round-11: round-0 structure (direct 64B stores, shuffle-network PV —
// rounds 1-3 proved nt-stores / K16-PV / LDS-burst-staging all regress).
// TWO coupled changes on the softmax math only:
//  (1) exp2f -> raw v_exp_f32 inline asm (skips OCML's denormal-guarded
//      multi-op expansion; exponents bounded so bit-safe).
//  (2) normalization folded into the pass-B MFMA accumulator init:
//      acc = {linv} with linv = -log2(rowsum) -> exp2(S+linv) is the
//      normalized prob directly; deletes 512 dependent v_mul per wave
//      and the reciprocal.
// ---------------------------------------------------------------------------
__global__ __launch_bounds__(256) void attn_kernel(
    const _Float16* __restrict__ Qf, const _Float16* __restrict__ Kf,
    const _Float16* __restrict__ VT,
    float* __restrict__ attn_out,     // [hb][q][k]
    _Float16* __restrict__ heads)     // [hb][q][e] fp16
{
    __shared__ float lred[4][2][16];
    __shared__ float Hred[4][32][33];

    const int tid = threadIdx.x;
    const int w = tid >> 6;
    const int l = tid & 63;
    const int lo4 = l & 15;
    const int g = l >> 4;
    // XCD swizzle: 2048 blocks = 16 hb x 128 qtiles; hb%8 == bid%8 == XCD
    const int bid = blockIdx.x;
    const int xcd = bid & 7;
    const int j = bid >> 3;
    const int hb = xcd + 8 * (j >> 7);
    const int q0 = (j & 127) * 32;

    const _Float16* Qb = Qf + (size_t)hb * SEQ * HD;
    const _Float16* Kb = Kf + (size_t)hb * SEQ * HD;
    const _Float16* Vb = VT + (size_t)hb * HD * SEQ;

    const f16x8 Bq0 = *(const f16x8*)(Qb + (size_t)(q0 + lo4) * HD + g * 8);
    const f16x8 Bq1 = *(const f16x8*)(Qb + (size_t)(q0 + 16 + lo4) * HD + g * 8);

    const int c_lo = w * 32, c_hi = c_lo + 32;   // contiguous per-wave k-range

    // ---------- pass A: row sums of exp2(s) ----------
    float ls0 = 0.f, ls1 = 0.f;
    for (int c = c_lo; c < c_hi; c++) {
        const int k0 = c * 32;
        #pragma unroll
        for (int s = 0; s < 2; s++) {
            f16x8 Ak = *(const f16x8*)(Kb + (size_t)(k0 + s * 16 + lo4) * HD + g * 8);
            f32x4 D0 = {0.f, 0.f, 0.f, 0.f}, D1 = {0.f, 0.f, 0.f, 0.f};
            D0 = MFMA16(Ak, Bq0, D0);
            D1 = MFMA16(Ak, Bq1, D1);
            ls0 += fast_exp2(D0[0]) + fast_exp2(D0[1]) + fast_exp2(D0[2]) + fast_exp2(D0[3]);
            ls1 += fast_exp2(D1[0]) + fast_exp2(D1[1]) + fast_exp2(D1[2]) + fast_exp2(D1[3]);
        }
    }
    ls0 += __shfl_xor(ls0, 16, 64); ls0 += __shfl_xor(ls0, 32, 64);
    ls1 += __shfl_xor(ls1, 16, 64); ls1 += __shfl_xor(ls1, 32, 64);
    if (l < 16) { lred[w][0][lo4] = ls0; lred[w][1][lo4] = ls1; }
    __syncthreads();
    const float sum0 = lred[0][0][lo4] + lred[1][0][lo4] + lred[2][0][lo4] + lred[3][0][lo4];
    const float sum1 = lred[0][1][lo4] + lred[1][1][lo4] + lred[2][1][lo4] + lred[3][1][lo4];
    const float linv0 = -fast_log2(sum0);   // exp2(S + linv) == exp2(S)/sum
    const float linv1 = -fast_log2(sum1);
    const f32x4 init0 = {linv0, linv0, linv0, linv0};   // all 4 D-elems share q=lo4
    const f32x4 init1 = {linv1, linv1, linv1, linv1};

    // ---------- pass B: recompute, write normalized probs, PV ----------
    f32x4 H00 = {0.f,0.f,0.f,0.f}, H01 = {0.f,0.f,0.f,0.f};
    f32x4 H10 = {0.f,0.f,0.f,0.f}, H11 = {0.f,0.f,0.f,0.f};
    float* ar0 = attn_out + ((size_t)hb * SEQ + q0 + lo4) * SEQ;
    float* ar1 = ar0 + (size_t)16 * SEQ;
    const int src0 = lo4 + ((g & 1) * 2) * 16;
    const int src1 = src0 + 16;

    for (int c = c_lo; c < c_hi; c++) {
        const int k0 = c * 32;
        uint_t w00[2], w01[2], w10[2], w11[2];
        #pragma unroll
        for (int s = 0; s < 2; s++) {
            f16x8 Ak = *(const f16x8*)(Kb + (size_t)(k0 + s * 16 + lo4) * HD + g * 8);
            f32x4 D0 = MFMA16(Ak, Bq0, init0);
            f32x4 D1 = MFMA16(Ak, Bq1, init1);
            float p00 = fast_exp2(D0[0]), p01 = fast_exp2(D0[1]);
            float p02 = fast_exp2(D0[2]), p03 = fast_exp2(D0[3]);
            float p10 = fast_exp2(D1[0]), p11 = fast_exp2(D1[1]);
            float p12 = fast_exp2(D1[2]), p13 = fast_exp2(D1[3]);
            *(float4*)(ar0 + k0 + s * 16 + g * 4) = make_float4(p00, p01, p02, p03);
            *(float4*)(ar1 + k0 + s * 16 + g * 4) = make_float4(p10, p11, p12, p13);
            w00[s] = pk16(p00, p01); w01[s] = pk16(p02, p03);
            w10[s] = pk16(p10, p11); w11[s] = pk16(p12, p13);
        }
        union { f16x8 v; uint_t u[4]; } P0, P1;
        {
            uint_t a, b2;
            a = __shfl(w00[0], src0, 64); b2 = __shfl(w00[1], src0, 64); P0.u[0] = (g >= 2) ? b2 : a;
            a = __shfl(w01[0], src0, 64); b2 = __shfl(w01[1], src0, 64); P0.u[1] = (g >= 2) ? b2 : a;
            a = __shfl(w00[0], src1, 64); b2 = __shfl(w00[1], src1, 64); P0.u[2] = (g >= 2) ? b2 : a;
            a = __shfl(w01[0], src1, 64); b2 = __shfl(w01[1], src1, 64); P0.u[3] = (g >= 2) ? b2 : a;
            a = __shfl(w10[0], src0, 64); b2 = __shfl(w10[1], src0, 64); P1.u[0] = (g >= 2) ? b2 : a;
            a = __shfl(w11[0], src0, 64); b2 = __shfl(w11[1], src0, 64); P1.u[1] = (g >= 2) ? b2 : a;
            a = __shfl(w10[0], src1, 64); b2 = __shfl(w10[1], src1, 64); P1.u[2] = (g >= 2) ? b2 : a;
            a = __shfl(w11[0], src1, 64); b2 = __shfl(w11[1], src1, 64); P1.u[3] = (g >= 2) ? b2 : a;
        }
        f16x8 Av0 = *(const f16x8*)(Vb + (size_t)lo4 * SEQ + k0 + g * 8);
        f16x8 Av1 = *(const f16x8*)(Vb + (size_t)(16 + lo4) * SEQ + k0 + g * 8);
        H00 = MFMA16(Av0, P0.v, H00);
        H01 = MFMA16(Av1, P0.v, H01);
        H10 = MFMA16(Av0, P1.v, H10);
        H11 = MFMA16(Av1, P1.v, H11);
    }

    #pragma unroll
    for (int r = 0; r < 4; r++) {
        Hred[w][lo4][g * 4 + r]            = H00[r];
        Hred[w][lo4][16 + g * 4 + r]       = H01[r];
        Hred[w][16 + lo4][g * 4 + r]       = H10[r];
        Hred[w][16 + lo4][16 + g * 4 + r]  = H11[r];
    }
    __syncthreads();
    for (int i = tid; i < 32 * 32; i += 256) {
        int qq = i >> 5, e = i & 31;
        float sum = Hred[0][qq][e] + Hred[1][qq][e] + Hred[2][qq][e] + Hred[3][qq][e];
        heads[((size_t)hb * SEQ + q0 + qq) * HD + e] = (_Float16)sum;
    }
}

// ---------------------------------------------------------------------------
// Kernel 3: output projection as MFMA GEMM.
// grid 128 x 256 thr: wave = 16 rows, all 256 out cols (16 col-tiles).
// out[r][o] = sum_he H[r][he] * (WoTh + WoTl)[o][he]
// ---------------------------------------------------------------------------
__global__ __launch_bounds__(256) void out_gemm_kernel(
    const _Float16* __restrict__ Hf,
    const _Float16* __restrict__ WoTh, const _Float16* __restrict__ WoTl,
    float* __restrict__ out)
{
    const int t = threadIdx.x, w = t >> 6, l = t & 63, lo4 = l & 15, g = l >> 4;
    const int r0 = blockIdx.x * 64 + w * 16;
    const int b = r0 >> 12;
    const int sb = r0 & (SEQ - 1);

    f16x8 A[8];
    #pragma unroll
    for (int kc = 0; kc < 8; kc++)
        A[kc] = *(const f16x8*)(Hf + (((size_t)(kc * BATCH + b)) * SEQ + sb + lo4) * HD + g * 8);

    for (int ct = 0; ct < 16; ct++) {
        f32x4 acc = {0.f, 0.f, 0.f, 0.f};
        const size_t woff = (size_t)(ct * 16 + lo4) * 256 + g * 8;
        #pragma unroll
        for (int kc = 0; kc < 8; kc++) {
            acc = MFMA16(A[kc], *(const f16x8*)(WoTh + woff + kc * 32), acc);
            acc = MFMA16(A[kc], *(const f16x8*)(WoTl + woff + kc * 32), acc);
        }
        #pragma unroll
        for (int r = 0; r < 4; r++)
            out[(size_t)(r0 + g * 4 + r) * 256 + ct * 16 + lo4] = acc[r];
    }
}

extern "C" void kernel_launch(void* const* d_in, const int* in_sizes, int n_in,
                              void* d_out, int out_size, void* d_ws, size_t ws_size,
                              hipStream_t stream) {
    const float* query = (const float*)d_in[0];
    const float* wq = (const float*)d_in[1];
    const float* wk = (const float*)d_in[2];
    const float* wv = (const float*)d_in[3];
    const float* wo = (const float*)d_in[4];
    float* out = (float*)d_out;
    float* attn_out = out + (size_t)BATCH * SEQ * EMB;

    _Float16* ws = (_Float16*)d_ws;
    const size_t nx  = (size_t)BATCH * SEQ * EMB;          // 2,097,152
    const size_t per = (size_t)HEADS * BATCH * SEQ * HD;   // 2,097,152
    _Float16* Xh   = ws;
    _Float16* Xl   = Xh + nx;
    _Float16* Wth  = Xl + nx;          // 196,608
    _Float16* Wtl  = Wth + 196608;
    _Float16* WoTh = Wtl + 196608;     // 65,536
    _Float16* WoTl = WoTh + 65536;
    _Float16* Qf   = WoTl + 65536;
    _Float16* Kf   = Qf + per;
    _Float16* VT   = Kf + per;
    _Float16* Hf   = VT + per;

    prep_x_kernel<<<(int)(nx / (256 * 8)), 256, 0, stream>>>(query, Xh, Xl);
    prep_w_kernel<<<256, 256, 0, stream>>>(wq, wk, wv, wo, Wth, Wtl, WoTh, WoTl);
    qkv_gemm_kernel<<<dim3((BATCH * SEQ) / 64, 3 * HEADS), 256, 0, stream>>>(
        Xh, Xl, Wth, Wtl, Qf, Kf, VT);
    attn_kernel<<<HEADS * BATCH * (SEQ / 32), 256, 0, stream>>>(
        Qf, Kf, VT, attn_out, Hf);
    out_gemm_kernel<<<(BATCH * SEQ) / 64, 256, 0, stream>>>(Hf, WoTh, WoTl, out);
}

// Round 5
// 426.006 us; speedup vs baseline: 1.1541x; 1.0301x over previous
//
#include <hip/hip_runtime.h>
#include <math.h>

#define EMB 256
#define HEADS 8
#define HD 32
#define BATCH 2
#define SEQ 4096
#define QSCALE 0.25504672075827703f   // (1/sqrt(32)) * log2(e)  -- exp2-folded softmax scale

typedef __attribute__((ext_vector_type(8))) _Float16 f16x8;
typedef __attribute__((ext_vector_type(4))) _Float16 f16x4;
typedef __attribute__((ext_vector_type(2))) __fp16 fp16x2_native;
typedef __attribute__((ext_vector_type(4))) float f32x4;
typedef unsigned int uint_t;

__device__ __forceinline__ uint_t pk16(float a, float b) {
    union { fp16x2_native h; uint_t u; } cv;
    cv.h = __builtin_amdgcn_cvt_pkrtz(a, b);
    return cv.u;
}

#define MFMA16(A, B, C) __builtin_amdgcn_mfma_f32_16x16x32_f16(A, B, C, 0, 0, 0)

// ---------------------------------------------------------------------------
// Prep 1: query fp32 -> Xh/Xl fp16 hi/lo split.  [r=b*4096+s][256]
// ---------------------------------------------------------------------------
__global__ __launch_bounds__(256) void prep_x_kernel(
    const float* __restrict__ q, _Float16* __restrict__ Xh, _Float16* __restrict__ Xl)
{
    const int i = (blockIdx.x * 256 + threadIdx.x) * 8;
    float4 v0 = *(const float4*)(q + i);
    float4 v1 = *(const float4*)(q + i + 4);
    float xs[8] = {v0.x, v0.y, v0.z, v0.w, v1.x, v1.y, v1.z, v1.w};
    f16x8 hv, lv;
    #pragma unroll
    for (int j = 0; j < 8; j++) {
        _Float16 h = (_Float16)xs[j];
        hv[j] = h;
        lv[j] = (_Float16)(xs[j] - (float)h);
    }
    *(f16x8*)(Xh + i) = hv;
    *(f16x8*)(Xl + i) = lv;
}

// ---------------------------------------------------------------------------
// Prep 2: weights -> transposed fp16 hi/lo.
//   Wth/Wtl: [p][h][e=32][d=256], QSCALE folded into p==0 (Wq)
//   WoTh/WoTl: [o=256][he=256]
// ---------------------------------------------------------------------------
__global__ __launch_bounds__(256) void prep_w_kernel(
    const float* __restrict__ wq, const float* __restrict__ wk,
    const float* __restrict__ wv, const float* __restrict__ wo,
    _Float16* __restrict__ Wth, _Float16* __restrict__ Wtl,
    _Float16* __restrict__ WoTh, _Float16* __restrict__ WoTl)
{
    for (int t = blockIdx.x * 256 + threadIdx.x; t < 262144; t += 256 * 256) {
        if (t < 196608) {
            int d = t & 255, e = (t >> 8) & 31, ph = t >> 13;
            int p = ph >> 3, h = ph & 7;
            const float* w = (p == 0) ? wq : (p == 1 ? wk : wv);
            float val = w[h * 8192 + d * 32 + e] * ((p == 0) ? QSCALE : 1.0f);
            _Float16 hi = (_Float16)val;
            Wth[t] = hi;
            Wtl[t] = (_Float16)(val - (float)hi);
        } else {
            int t2 = t - 196608;
            int he = t2 & 255, o = t2 >> 8;
            float val = wo[(he >> 5) * 8192 + (he & 31) * 256 + o];
            _Float16 hi = (_Float16)val;
            WoTh[t2] = hi;
            WoTl[t2] = (_Float16)(val - (float)hi);
        }
    }
}

// ---------------------------------------------------------------------------
// Kernel 1: QKV projection as MFMA GEMM, no LDS staging of operands.
// grid (128, 24): x = 64-row tile (wave = 16 rows), y = p*8+h.
// D[s][e] = Xh*Wh + Xl*Wh + Xh*Wl   (fp32-grade via hi/lo split)
// Q/K: LDS-staged 64B-row writes.  V: direct VT[e][s] f16x4 writes.
// ---------------------------------------------------------------------------
__global__ __launch_bounds__(256) void qkv_gemm_kernel(
    const _Float16* __restrict__ Xh, const _Float16* __restrict__ Xl,
    const _Float16* __restrict__ Wth, const _Float16* __restrict__ Wtl,
    _Float16* __restrict__ Qf, _Float16* __restrict__ Kf, _Float16* __restrict__ VT)
{
    __shared__ _Float16 st[4][16][32];
    const int t = threadIdx.x, w = t >> 6, l = t & 63, lo4 = l & 15, g = l >> 4;
    const int tile = blockIdx.x, ph = blockIdx.y, p = ph >> 3, h = ph & 7;
    const int r0 = tile * 64 + w * 16;
    const int b = (tile * 64) >> 12;
    const int s_base = (tile * 64) & (SEQ - 1);
    const int hb = h * BATCH + b;

    f16x8 Ah[8], Al[8];
    const size_t xoff = (size_t)(r0 + lo4) * 256 + g * 8;
    #pragma unroll
    for (int kc = 0; kc < 8; kc++) {
        Ah[kc] = *(const f16x8*)(Xh + xoff + kc * 32);
        Al[kc] = *(const f16x8*)(Xl + xoff + kc * 32);
    }

    f32x4 D[2];
    #pragma unroll
    for (int ct = 0; ct < 2; ct++) {
        f32x4 acc = {0.f, 0.f, 0.f, 0.f};
        const size_t woff = (size_t)(ph * 32 + ct * 16 + lo4) * 256 + g * 8;
        #pragma unroll
        for (int kc = 0; kc < 8; kc++) {
            f16x8 Bh = *(const f16x8*)(Wth + woff + kc * 32);
            f16x8 Bl = *(const f16x8*)(Wtl + woff + kc * 32);
            acc = MFMA16(Ah[kc], Bh, acc);
            acc = MFMA16(Al[kc], Bh, acc);
            acc = MFMA16(Ah[kc], Bl, acc);
        }
        D[ct] = acc;
    }

    if (p < 2) {
        #pragma unroll
        for (int ct = 0; ct < 2; ct++)
            #pragma unroll
            for (int r = 0; r < 4; r++)
                st[w][g * 4 + r][ct * 16 + lo4] = (_Float16)D[ct][r];
        __syncthreads();
        _Float16* dst = (p == 0) ? Qf : Kf;
        const int rl = t >> 2, e8 = (t & 3) * 8;   // rl = 0..63 local row
        *(f16x8*)(dst + ((size_t)hb * SEQ + s_base + rl) * HD + e8) =
            *(f16x8*)&st[rl >> 4][rl & 15][e8];
    } else {
        #pragma unroll
        for (int ct = 0; ct < 2; ct++) {
            f16x4 v;
            #pragma unroll
            for (int r = 0; r < 4; r++) v[r] = (_Float16)D[ct][r];
            *(f16x4*)(VT + ((size_t)hb * HD + ct * 16 + lo4) * SEQ + s_base + w * 16 + g * 4) = v;
        }
    }
}

// ---------------------------------------------------------------------------
// Kernel 2: fused attention, two-pass no-max softmax (exp2-domain), fp16 MFMA.
// Round-12: EXACT round-0 structure (exp2f, inv-mul normalize, shuffle PV,
// direct 64B stores) + ONE change: pass B is 1-deep software-pipelined.
// K/V loads for chunk c+1 issue at the TOP of iteration c, BEFORE the
// stores of iteration c.  vmcnt is a single in-order counter shared by
// loads and stores; in round-0's order (loads(c+1) issued after stores(c))
// the s_waitcnt before each MFMA could only be satisfied by draining all
// prior stores with zero slack -- serializing compute behind the HBM-paced
// write drain.  With loads hoisted ahead of stores, each wait is
// vmcnt(~8) and each store batch gets a full iteration of drain slack.
// Last iteration overreads one 32-k chunk into the adjacent workspace
// buffer (Kf->VT, VT->Hf); values unused.
// ---------------------------------------------------------------------------
__global__ __launch_bounds__(256) void attn_kernel(
    const _Float16* __restrict__ Qf, const _Float16* __restrict__ Kf,
    const _Float16* __restrict__ VT,
    float* __restrict__ attn_out,     // [hb][q][k]
    _Float16* __restrict__ heads)     // [hb][q][e] fp16
{
    __shared__ float lred[4][2][16];
    __shared__ float Hred[4][32][33];

    const int tid = threadIdx.x;
    const int w = tid >> 6;
    const int l = tid & 63;
    const int lo4 = l & 15;
    const int g = l >> 4;
    // XCD swizzle: 2048 blocks = 16 hb x 128 qtiles; hb%8 == bid%8 == XCD
    const int bid = blockIdx.x;
    const int xcd = bid & 7;
    const int j = bid >> 3;
    const int hb = xcd + 8 * (j >> 7);
    const int q0 = (j & 127) * 32;

    const _Float16* Qb = Qf + (size_t)hb * SEQ * HD;
    const _Float16* Kb = Kf + (size_t)hb * SEQ * HD;
    const _Float16* Vb = VT + (size_t)hb * HD * SEQ;

    const f16x8 Bq0 = *(const f16x8*)(Qb + (size_t)(q0 + lo4) * HD + g * 8);
    const f16x8 Bq1 = *(const f16x8*)(Qb + (size_t)(q0 + 16 + lo4) * HD + g * 8);

    const int c_lo = w * 32, c_hi = c_lo + 32;   // contiguous per-wave k-range

    // ---------- pass A: row sums of exp2(s) ----------
    float ls0 = 0.f, ls1 = 0.f;
    for (int c = c_lo; c < c_hi; c++) {
        const int k0 = c * 32;
        #pragma unroll
        for (int s = 0; s < 2; s++) {
            f16x8 Ak = *(const f16x8*)(Kb + (size_t)(k0 + s * 16 + lo4) * HD + g * 8);
            f32x4 D0 = {0.f, 0.f, 0.f, 0.f}, D1 = {0.f, 0.f, 0.f, 0.f};
            D0 = MFMA16(Ak, Bq0, D0);
            D1 = MFMA16(Ak, Bq1, D1);
            ls0 += exp2f(D0[0]) + exp2f(D0[1]) + exp2f(D0[2]) + exp2f(D0[3]);
            ls1 += exp2f(D1[0]) + exp2f(D1[1]) + exp2f(D1[2]) + exp2f(D1[3]);
        }
    }
    ls0 += __shfl_xor(ls0, 16, 64); ls0 += __shfl_xor(ls0, 32, 64);
    ls1 += __shfl_xor(ls1, 16, 64); ls1 += __shfl_xor(ls1, 32, 64);
    if (l < 16) { lred[w][0][lo4] = ls0; lred[w][1][lo4] = ls1; }
    __syncthreads();
    const float inv0 = 1.0f / (lred[0][0][lo4] + lred[1][0][lo4] + lred[2][0][lo4] + lred[3][0][lo4]);
    const float inv1 = 1.0f / (lred[0][1][lo4] + lred[1][1][lo4] + lred[2][1][lo4] + lred[3][1][lo4]);

    // ---------- pass B: 1-deep pipelined recompute, write probs, PV ----------
    f32x4 H00 = {0.f,0.f,0.f,0.f}, H01 = {0.f,0.f,0.f,0.f};
    f32x4 H10 = {0.f,0.f,0.f,0.f}, H11 = {0.f,0.f,0.f,0.f};
    float* ar0 = attn_out + ((size_t)hb * SEQ + q0 + lo4) * SEQ;
    float* ar1 = ar0 + (size_t)16 * SEQ;
    const int src0 = lo4 + ((g & 1) * 2) * 16;
    const int src1 = src0 + 16;

    // prologue: loads for c_lo
    f16x8 cAk0 = *(const f16x8*)(Kb + (size_t)(c_lo * 32 + lo4) * HD + g * 8);
    f16x8 cAk1 = *(const f16x8*)(Kb + (size_t)(c_lo * 32 + 16 + lo4) * HD + g * 8);
    f16x8 cAv0 = *(const f16x8*)(Vb + (size_t)lo4 * SEQ + c_lo * 32 + g * 8);
    f16x8 cAv1 = *(const f16x8*)(Vb + (size_t)(16 + lo4) * SEQ + c_lo * 32 + g * 8);

    for (int c = c_lo; c < c_hi; c++) {
        const int k0 = c * 32;
        const int k0n = k0 + 32;   // next chunk; last iter overreads into workspace
        f16x8 nAk0 = *(const f16x8*)(Kb + (size_t)(k0n + lo4) * HD + g * 8);
        f16x8 nAk1 = *(const f16x8*)(Kb + (size_t)(k0n + 16 + lo4) * HD + g * 8);
        f16x8 nAv0 = *(const f16x8*)(Vb + (size_t)lo4 * SEQ + k0n + g * 8);
        f16x8 nAv1 = *(const f16x8*)(Vb + (size_t)(16 + lo4) * SEQ + k0n + g * 8);

        uint_t w00[2], w01[2], w10[2], w11[2];
        #pragma unroll
        for (int s = 0; s < 2; s++) {
            f16x8 Ak = (s == 0) ? cAk0 : cAk1;
            f32x4 D0 = {0.f, 0.f, 0.f, 0.f}, D1 = {0.f, 0.f, 0.f, 0.f};
            D0 = MFMA16(Ak, Bq0, D0);
            D1 = MFMA16(Ak, Bq1, D1);
            float p00 = exp2f(D0[0]) * inv0, p01 = exp2f(D0[1]) * inv0;
            float p02 = exp2f(D0[2]) * inv0, p03 = exp2f(D0[3]) * inv0;
            float p10 = exp2f(D1[0]) * inv1, p11 = exp2f(D1[1]) * inv1;
            float p12 = exp2f(D1[2]) * inv1, p13 = exp2f(D1[3]) * inv1;
            *(float4*)(ar0 + k0 + s * 16 + g * 4) = make_float4(p00, p01, p02, p03);
            *(float4*)(ar1 + k0 + s * 16 + g * 4) = make_float4(p10, p11, p12, p13);
            w00[s] = pk16(p00, p01); w01[s] = pk16(p02, p03);
            w10[s] = pk16(p10, p11); w11[s] = pk16(p12, p13);
        }
        union { f16x8 v; uint_t u[4]; } P0, P1;
        {
            uint_t a, b2;
            a = __shfl(w00[0], src0, 64); b2 = __shfl(w00[1], src0, 64); P0.u[0] = (g >= 2) ? b2 : a;
            a = __shfl(w01[0], src0, 64); b2 = __shfl(w01[1], src0, 64); P0.u[1] = (g >= 2) ? b2 : a;
            a = __shfl(w00[0], src1, 64); b2 = __shfl(w00[1], src1, 64); P0.u[2] = (g >= 2) ? b2 : a;
            a = __shfl(w01[0], src1, 64); b2 = __shfl(w01[1], src1, 64); P0.u[3] = (g >= 2) ? b2 : a;
            a = __shfl(w10[0], src0, 64); b2 = __shfl(w10[1], src0, 64); P1.u[0] = (g >= 2) ? b2 : a;
            a = __shfl(w11[0], src0, 64); b2 = __shfl(w11[1], src0, 64); P1.u[1] = (g >= 2) ? b2 : a;
            a = __shfl(w10[0], src1, 64); b2 = __shfl(w10[1], src1, 64); P1.u[2] = (g >= 2) ? b2 : a;
            a = __shfl(w11[0], src1, 64); b2 = __shfl(w11[1], src1, 64); P1.u[3] = (g >= 2) ? b2 : a;
        }
        H00 = MFMA16(cAv0, P0.v, H00);
        H01 = MFMA16(cAv1, P0.v, H01);
        H10 = MFMA16(cAv0, P1.v, H10);
        H11 = MFMA16(cAv1, P1.v, H11);

        cAk0 = nAk0; cAk1 = nAk1; cAv0 = nAv0; cAv1 = nAv1;
    }

    #pragma unroll
    for (int r = 0; r < 4; r++) {
        Hred[w][lo4][g * 4 + r]            = H00[r];
        Hred[w][lo4][16 + g * 4 + r]       = H01[r];
        Hred[w][16 + lo4][g * 4 + r]       = H10[r];
        Hred[w][16 + lo4][16 + g * 4 + r]  = H11[r];
    }
    __syncthreads();
    for (int i = tid; i < 32 * 32; i += 256) {
        int qq = i >> 5, e = i & 31;
        float sum = Hred[0][qq][e] + Hred[1][qq][e] + Hred[2][qq][e] + Hred[3][qq][e];
        heads[((size_t)hb * SEQ + q0 + qq) * HD + e] = (_Float16)sum;
    }
}

// ---------------------------------------------------------------------------
// Kernel 3: output projection as MFMA GEMM.
// grid 128 x 256 thr: wave = 16 rows, all 256 out cols (16 col-tiles).
// out[r][o] = sum_he H[r][he] * (WoTh + WoTl)[o][he]
// ---------------------------------------------------------------------------
__global__ __launch_bounds__(256) void out_gemm_kernel(
    const _Float16* __restrict__ Hf,
    const _Float16* __restrict__ WoTh, const _Float16* __restrict__ WoTl,
    float* __restrict__ out)
{
    const int t = threadIdx.x, w = t >> 6, l = t & 63, lo4 = l & 15, g = l >> 4;
    const int r0 = blockIdx.x * 64 + w * 16;
    const int b = r0 >> 12;
    const int sb = r0 & (SEQ - 1);

    f16x8 A[8];
    #pragma unroll
    for (int kc = 0; kc < 8; kc++)
        A[kc] = *(const f16x8*)(Hf + (((size_t)(kc * BATCH + b)) * SEQ + sb + lo4) * HD + g * 8);

    for (int ct = 0; ct < 16; ct++) {
        f32x4 acc = {0.f, 0.f, 0.f, 0.f};
        const size_t woff = (size_t)(ct * 16 + lo4) * 256 + g * 8;
        #pragma unroll
        for (int kc = 0; kc < 8; kc++) {
            acc = MFMA16(A[kc], *(const f16x8*)(WoTh + woff + kc * 32), acc);
            acc = MFMA16(A[kc], *(const f16x8*)(WoTl + woff + kc * 32), acc);
        }
        #pragma unroll
        for (int r = 0; r < 4; r++)
            out[(size_t)(r0 + g * 4 + r) * 256 + ct * 16 + lo4] = acc[r];
    }
}

extern "C" void kernel_launch(void* const* d_in, const int* in_sizes, int n_in,
                              void* d_out, int out_size, void* d_ws, size_t ws_size,
                              hipStream_t stream) {
    const float* query = (const float*)d_in[0];
    const float* wq = (const float*)d_in[1];
    const float* wk = (const float*)d_in[2];
    const float* wv = (const float*)d_in[3];
    const float* wo = (const float*)d_in[4];
    float* out = (float*)d_out;
    float* attn_out = out + (size_t)BATCH * SEQ * EMB;

    _Float16* ws = (_Float16*)d_ws;
    const size_t nx  = (size_t)BATCH * SEQ * EMB;          // 2,097,152
    const size_t per = (size_t)HEADS * BATCH * SEQ * HD;   // 2,097,152
    _Float16* Xh   = ws;
    _Float16* Xl   = Xh + nx;
    _Float16* Wth  = Xl + nx;          // 196,608
    _Float16* Wtl  = Wth + 196608;
    _Float16* WoTh = Wtl + 196608;     // 65,536
    _Float16* WoTl = WoTh + 65536;
    _Float16* Qf   = WoTl + 65536;
    _Float16* Kf   = Qf + per;
    _Float16* VT   = Kf + per;
    _Float16* Hf   = VT + per;

    prep_x_kernel<<<(int)(nx / (256 * 8)), 256, 0, stream>>>(query, Xh, Xl);
    prep_w_kernel<<<256, 256, 0, stream>>>(wq, wk, wv, wo, Wth, Wtl, WoTh, WoTl);
    qkv_gemm_kernel<<<dim3((BATCH * SEQ) / 64, 3 * HEADS), 256, 0, stream>>>(
        Xh, Xl, Wth, Wtl, Qf, Kf, VT);
    attn_kernel<<<HEADS * BATCH * (SEQ / 32), 256, 0, stream>>>(
        Qf, Kf, VT, attn_out, Hf);
    out_gemm_kernel<<<(BATCH * SEQ) / 64, 256, 0, stream>>>(Hf, WoTh, WoTl, out);
}